// Round 3
// baseline (518.024 us; speedup 1.0000x reference)
//
#include <hip/hip_runtime.h>

// NT-Xent loss, B=4096, D=256, N=16384, T=0.5.
// loss = mean_i( -pos_i + log(sum_{j!=i} exp(2*dot(zn_i, zn_j)) + 1e-12) )
//
// R3: LDS-free "flatmm" Gram kernel. Both MFMA operand fragments of a Gram
// matrix are contiguous 16B row-segments of zb -> direct global bf16x8 loads
// with immediate offsets; no staging, no K-loop barriers. zb pre-scaled by
// sqrt(2) so exp(acc) needs no multiply. R1's supertile/XCD swizzle restored
// (16384-grid decode, early-exit on lower triangle) for L2 locality.
//
// ws layout:
//   [0, 8MB)            : zb   — l2-normalized z * sqrt(2), bf16, [16384][256]
//   [8MB, 16MB)         : part — per-colblock row sums, f32, [128][16384]
//   [16MB, 16MB+16KB)   : pospart[4096]
//   [16MB+16KB, +256B)  : logpart[64]
// Every ws slot is written exactly once per launch -> no memset needed.

typedef __bf16 bf16;
typedef __bf16 bf16x4 __attribute__((ext_vector_type(4)));
typedef __bf16 bf16x8 __attribute__((ext_vector_type(8)));
typedef float  f32x4  __attribute__((ext_vector_type(4)));

#define NTOT 16384
#define DDIM 256

__device__ __forceinline__ float dot4(float4 a, float4 b) {
    return a.x * b.x + a.y * b.y + a.z * b.z + a.w * b.w;
}

// ---------------- kernel 1: normalize rows -> bf16*sqrt2, plus positive-pair sims ----------------
__global__ __launch_bounds__(256) void norm4k(const float* __restrict__ z1,
                                              const float* __restrict__ z2,
                                              const float* __restrict__ z3,
                                              const float* __restrict__ z4,
                                              bf16* __restrict__ zb,
                                              float* __restrict__ pospart) {
    const int wave = threadIdx.x >> 6;
    const int lane = threadIdx.x & 63;
    const int i    = blockIdx.x * 4 + wave; // 0..4095
    const float4* p1 = (const float4*)(z1 + (size_t)i * DDIM);
    const float4* p2 = (const float4*)(z2 + (size_t)i * DDIM);
    const float4* p3 = (const float4*)(z3 + (size_t)i * DDIM);
    const float4* p4 = (const float4*)(z4 + (size_t)i * DDIM);
    float4 a = p1[lane], b = p2[lane], c = p3[lane], d = p4[lane];
    float s11 = dot4(a, a), s22 = dot4(b, b), s33 = dot4(c, c), s44 = dot4(d, d);
    float s12 = dot4(a, b), s23 = dot4(b, c), s34 = dot4(c, d), s41 = dot4(d, a);
#pragma unroll
    for (int m = 32; m >= 1; m >>= 1) {
        s11 += __shfl_xor(s11, m, 64); s22 += __shfl_xor(s22, m, 64);
        s33 += __shfl_xor(s33, m, 64); s44 += __shfl_xor(s44, m, 64);
        s12 += __shfl_xor(s12, m, 64); s23 += __shfl_xor(s23, m, 64);
        s34 += __shfl_xor(s34, m, 64); s41 += __shfl_xor(s41, m, 64);
    }
    const float m1 = fmaxf(sqrtf(s11), 1e-12f), m2 = fmaxf(sqrtf(s22), 1e-12f);
    const float m3 = fmaxf(sqrtf(s33), 1e-12f), m4 = fmaxf(sqrtf(s44), 1e-12f);
    const float i1 = 1.0f / m1, i2 = 1.0f / m2, i3 = 1.0f / m3, i4 = 1.0f / m4;
    const float R2 = 1.41421356237f;
    const float a1 = i1 * R2, a2 = i2 * R2, a3 = i3 * R2, a4 = i4 * R2;
    bf16x4 o;
    o.x = (bf16)(a.x * a1); o.y = (bf16)(a.y * a1); o.z = (bf16)(a.z * a1); o.w = (bf16)(a.w * a1);
    *(bf16x4*)(zb + (size_t)i * DDIM + lane * 4) = o;
    o.x = (bf16)(b.x * a2); o.y = (bf16)(b.y * a2); o.z = (bf16)(b.z * a2); o.w = (bf16)(b.w * a2);
    *(bf16x4*)(zb + (size_t)(i + 4096) * DDIM + lane * 4) = o;
    o.x = (bf16)(c.x * a3); o.y = (bf16)(c.y * a3); o.z = (bf16)(c.z * a3); o.w = (bf16)(c.w * a3);
    *(bf16x4*)(zb + (size_t)(i + 8192) * DDIM + lane * 4) = o;
    o.x = (bf16)(d.x * a4); o.y = (bf16)(d.y * a4); o.z = (bf16)(d.z * a4); o.w = (bf16)(d.w * a4);
    *(bf16x4*)(zb + (size_t)(i + 12288) * DDIM + lane * 4) = o;
    if (lane == 0)
        pospart[i] = 2.0f * (s12 * i1 * i2 + s23 * i2 * i3 + s34 * i3 * i4 + s41 * i4 * i1);
}

// ---------------- kernel 2: LDS-free fused Gram exp-rowsum, upper triangle ----------------
// 128x128 tile per block; 4 waves in 2x2 of 64x64; mfma_f32_16x16x32_bf16.
// All operand fragments loaded straight from global (contiguous 16B segments).
__global__ __launch_bounds__(256, 4) void tilek(const bf16* __restrict__ zb,
                                                float* __restrict__ part) {
    __shared__ float rsum_lds[2][128];
    __shared__ float csum_lds[2][128];

    const int tid  = threadIdx.x;
    const int wave = tid >> 6;
    const int lane = tid & 63;

    // R1 supertile/XCD swizzle on the full 128x128 block grid; skip lower triangle.
    const int bid    = blockIdx.x;
    const int xcd    = bid & 7;
    const int j      = bid >> 3;
    const int super  = ((j >> 8) << 3) + xcd;          // 0..63
    const int within = j & 255;
    const int brow   = ((super >> 3) << 4) + (within >> 4);  // 0..127
    const int bcol   = ((super & 7) << 4) + (within & 15);   // 0..127
    if (brow > bcol) return;
    const bool isdiag = (brow == bcol);

    const int quad = lane >> 4;
    const int l15  = lane & 15;
    const int wr   = wave >> 1, wc = wave & 1;

    // per-rt/ct fragment base pointers (row stride 512B); K offsets are immediates
    const char* ap[4];
    const char* bp[4];
#pragma unroll
    for (int t = 0; t < 4; ++t) {
        int arow = brow * 128 + (wr << 6) + (t << 4) + l15;
        int brw  = bcol * 128 + (wc << 6) + (t << 4) + l15;
        ap[t] = (const char*)zb + (size_t)arow * 512 + (quad << 4);
        bp[t] = (const char*)zb + (size_t)brw  * 512 + (quad << 4);
    }

    f32x4 zero = {0.f, 0.f, 0.f, 0.f};
    f32x4 acc[4][4];
#pragma unroll
    for (int a = 0; a < 4; ++a)
#pragma unroll
        for (int b = 0; b < 4; ++b) acc[a][b] = zero;

#pragma unroll
    for (int ks = 0; ks < 8; ++ks) {       // K = 8 x 32
        bf16x8 af[4], bfr[4];
#pragma unroll
        for (int t = 0; t < 4; ++t) {
            af[t]  = *(const bf16x8*)(ap[t] + ks * 64);
            bfr[t] = *(const bf16x8*)(bp[t] + ks * 64);
        }
#pragma unroll
        for (int rt = 0; rt < 4; ++rt)
#pragma unroll
            for (int ct = 0; ct < 4; ++ct)
                acc[rt][ct] = __builtin_amdgcn_mfma_f32_16x16x32_bf16(
                    af[rt], bfr[ct], acc[rt][ct], 0, 0, 0);
    }

    // epilogue: e = exp(acc) (inputs pre-scaled by sqrt2 -> acc = 2*cos_sim);
    // mask diagonal; row-sums over lane&15, col-sums over quad.
    const int rb = wr << 6;
    const int cb = wc << 6;
    float cs[4] = {0.f, 0.f, 0.f, 0.f};
#pragma unroll
    for (int rt = 0; rt < 4; ++rt) {
        float rs[4] = {0.f, 0.f, 0.f, 0.f};
        const int rtile = rb + (rt << 4);
#pragma unroll
        for (int ct = 0; ct < 4; ++ct) {
            const int ctile = cb + (ct << 4);
            const bool tdiag = isdiag && (rtile == ctile);
#pragma unroll
            for (int r = 0; r < 4; ++r) {
                float e = __expf(acc[rt][ct][r]);
                if (tdiag && ((quad << 2) + r) == l15) e = 0.f; // self-sim
                rs[r] += e;
                cs[ct] += e;
            }
        }
#pragma unroll
        for (int m = 1; m <= 8; m <<= 1)
#pragma unroll
            for (int r = 0; r < 4; ++r) rs[r] += __shfl_xor(rs[r], m, 64);
        if (l15 == 0) {
            int lrow = rb + (rt << 4) + (quad << 2);
#pragma unroll
            for (int r = 0; r < 4; ++r) rsum_lds[wc][lrow + r] = rs[r];
        }
    }
#pragma unroll
    for (int m = 16; m <= 32; m <<= 1)
#pragma unroll
        for (int ct = 0; ct < 4; ++ct) cs[ct] += __shfl_xor(cs[ct], m, 64);
    if (quad == 0) {
#pragma unroll
        for (int ct = 0; ct < 4; ++ct) csum_lds[wr][cb + (ct << 4) + l15] = cs[ct];
    }
    __syncthreads();
    if (tid < 128) {
        float rv = rsum_lds[0][tid] + rsum_lds[1][tid];
        part[(size_t)bcol * NTOT + brow * 128 + tid] = rv;
        if (!isdiag) {
            float cv = csum_lds[0][tid] + csum_lds[1][tid];
            part[(size_t)brow * NTOT + bcol * 128 + tid] = cv;
        }
    }
}

// ---------------- kernel 3: reduce partials per row, take log ----------------
__global__ __launch_bounds__(256) void rowlog(const float* __restrict__ part,
                                              float* __restrict__ logpart) {
    const int row = blockIdx.x * 256 + threadIdx.x;
    float s = 0.f;
    for (int c = 0; c < 128; ++c) s += part[(size_t)c * NTOT + row];
    float lg = logf(s + 1e-12f);
#pragma unroll
    for (int m = 32; m >= 1; m >>= 1) lg += __shfl_xor(lg, m, 64);
    __shared__ float red[4];
    const int wave = threadIdx.x >> 6, lane = threadIdx.x & 63;
    if (lane == 0) red[wave] = lg;
    __syncthreads();
    if (threadIdx.x == 0) logpart[blockIdx.x] = red[0] + red[1] + red[2] + red[3];
}

// ---------------- kernel 4: finalize ----------------
__global__ __launch_bounds__(256) void finalk(const float* __restrict__ pospart,
                                              const float* __restrict__ logpart,
                                              float* __restrict__ out) {
    const int t = threadIdx.x;
    float sp = 0.f, sl = 0.f;
    for (int k = t; k < 4096; k += 256) sp += pospart[k];
    if (t < 64) sl = logpart[t];
#pragma unroll
    for (int m = 32; m >= 1; m >>= 1) { sp += __shfl_xor(sp, m, 64); sl += __shfl_xor(sl, m, 64); }
    __shared__ float rp[4], rl[4];
    const int wave = t >> 6, lane = t & 63;
    if (lane == 0) { rp[wave] = sp; rl[wave] = sl; }
    __syncthreads();
    if (t == 0) {
        float P = rp[0] + rp[1] + rp[2] + rp[3];
        float L = rl[0] + rl[1] + rl[2] + rl[3];
        out[0] = (L - P) / 16384.0f;
    }
}

extern "C" void kernel_launch(void* const* d_in, const int* in_sizes, int n_in,
                              void* d_out, int out_size, void* d_ws, size_t ws_size,
                              hipStream_t stream) {
    const float* z1 = (const float*)d_in[0];
    const float* z2 = (const float*)d_in[1];
    const float* z3 = (const float*)d_in[2];
    const float* z4 = (const float*)d_in[3];
    float* out = (float*)d_out;

    char* ws = (char*)d_ws;
    bf16*  zb      = (bf16*)ws;                                  // 8 MB
    float* part    = (float*)(ws + (size_t)(8u << 20));          // 8 MB
    float* pospart = (float*)(ws + (size_t)(16u << 20));         // 16 KB
    float* logpart = (float*)(ws + (size_t)(16u << 20) + 16384); // 256 B

    norm4k<<<1024, 256, 0, stream>>>(z1, z2, z3, z4, zb, pospart);
    tilek<<<16384, 256, 0, stream>>>(zb, part);
    rowlog<<<64, 256, 0, stream>>>(part, logpart);
    finalk<<<1, 256, 0, stream>>>(pospart, logpart, out);
}

// Round 4
// 216.342 us; speedup vs baseline: 2.3945x; 2.3945x over previous
//
#include <hip/hip_runtime.h>

// NT-Xent loss, B=4096, D=256, N=16384, T=0.5.
// loss = mean_i( -pos_i + log(sum_{j!=i} exp(2*dot(zn_i, zn_j)) + 1e-12) )
//
// R4: back to the R2 LDS-staged structure (R3's LDS-free gather was latency-
// bound: MfmaUtil 5.8%). Gram operands in fp8 e4m3 via the MX-scaled
// mfma_scale_f32_16x16x128_f8f6f4 (scales=1.0) -> 2x MFMA rate, half the
// ds_reads/staging/barriers per block. zb is 4MB (L2-resident); R1 supertile/
// XCD swizzle restored via 16384-grid decode with lower-triangle early-exit.
// pos terms exact fp32. Triangular both-sum epilogue identical to R2 (verified).
//
// ws layout:
//   [0, 4MB)            : zq   — l2-normalized z, fp8 e4m3, [16384][256]
//   [4MB, 12MB)         : part — per-colblock row sums, f32, [128][16384]
//   [12MB, 12MB+16KB)   : pospart[4096]
//   [12MB+16KB, +256B)  : logpart[64]
// Every ws slot is written exactly once per launch -> no memset needed.

typedef float f32x4 __attribute__((ext_vector_type(4)));
typedef int   i32x4 __attribute__((ext_vector_type(4)));
typedef int   i32x8 __attribute__((ext_vector_type(8)));

#define NTOT 16384
#define DDIM 256
#define TWO_OVER_LN2 2.8853900817779268f

__device__ __forceinline__ float dot4(float4 a, float4 b) {
    return a.x * b.x + a.y * b.y + a.z * b.z + a.w * b.w;
}

// ---------------- kernel 1: normalize rows -> fp8 e4m3, plus positive-pair sims ----------------
__global__ __launch_bounds__(256) void norm4k(const float* __restrict__ z1,
                                              const float* __restrict__ z2,
                                              const float* __restrict__ z3,
                                              const float* __restrict__ z4,
                                              unsigned int* __restrict__ zq,
                                              float* __restrict__ pospart) {
    const int wave = threadIdx.x >> 6;
    const int lane = threadIdx.x & 63;
    const int i    = blockIdx.x * 4 + wave; // 0..4095
    const float4* p1 = (const float4*)(z1 + (size_t)i * DDIM);
    const float4* p2 = (const float4*)(z2 + (size_t)i * DDIM);
    const float4* p3 = (const float4*)(z3 + (size_t)i * DDIM);
    const float4* p4 = (const float4*)(z4 + (size_t)i * DDIM);
    float4 a = p1[lane], b = p2[lane], c = p3[lane], d = p4[lane];
    float s11 = dot4(a, a), s22 = dot4(b, b), s33 = dot4(c, c), s44 = dot4(d, d);
    float s12 = dot4(a, b), s23 = dot4(b, c), s34 = dot4(c, d), s41 = dot4(d, a);
#pragma unroll
    for (int m = 32; m >= 1; m >>= 1) {
        s11 += __shfl_xor(s11, m, 64); s22 += __shfl_xor(s22, m, 64);
        s33 += __shfl_xor(s33, m, 64); s44 += __shfl_xor(s44, m, 64);
        s12 += __shfl_xor(s12, m, 64); s23 += __shfl_xor(s23, m, 64);
        s34 += __shfl_xor(s34, m, 64); s41 += __shfl_xor(s41, m, 64);
    }
    const float m1 = fmaxf(sqrtf(s11), 1e-12f), m2 = fmaxf(sqrtf(s22), 1e-12f);
    const float m3 = fmaxf(sqrtf(s33), 1e-12f), m4 = fmaxf(sqrtf(s44), 1e-12f);
    const float i1 = 1.0f / m1, i2 = 1.0f / m2, i3 = 1.0f / m3, i4 = 1.0f / m4;
    unsigned int u;
    u = __builtin_amdgcn_cvt_pk_fp8_f32(a.x * i1, a.y * i1, 0, false);
    u = __builtin_amdgcn_cvt_pk_fp8_f32(a.z * i1, a.w * i1, u, true);
    zq[(size_t)i * 64 + lane] = u;
    u = __builtin_amdgcn_cvt_pk_fp8_f32(b.x * i2, b.y * i2, 0, false);
    u = __builtin_amdgcn_cvt_pk_fp8_f32(b.z * i2, b.w * i2, u, true);
    zq[(size_t)(i + 4096) * 64 + lane] = u;
    u = __builtin_amdgcn_cvt_pk_fp8_f32(c.x * i3, c.y * i3, 0, false);
    u = __builtin_amdgcn_cvt_pk_fp8_f32(c.z * i3, c.w * i3, u, true);
    zq[(size_t)(i + 8192) * 64 + lane] = u;
    u = __builtin_amdgcn_cvt_pk_fp8_f32(d.x * i4, d.y * i4, 0, false);
    u = __builtin_amdgcn_cvt_pk_fp8_f32(d.z * i4, d.w * i4, u, true);
    zq[(size_t)(i + 12288) * 64 + lane] = u;
    if (lane == 0)
        pospart[i] = 2.0f * (s12 * i1 * i2 + s23 * i2 * i3 + s34 * i3 * i4 + s41 * i4 * i1);
}

// ---------------- kernel 2: staged MX-fp8 Gram exp-rowsum, upper triangle ----------------
// 128x128 tile per block; 4 waves in 2x2 of 64x64; mfma_scale_f32_16x16x128_f8f6f4.
// LDS granule-xor swizzle: granule g (16B) of row r stored at slot (g ^ (r&7)).
__global__ __launch_bounds__(256, 3) void tilek(const unsigned char* __restrict__ zq,
                                                float* __restrict__ part) {
    __shared__ __attribute__((aligned(16))) char lds[32768]; // A:[0,16K) B:[16K,32K)
    __shared__ float rsum_lds[2][128];
    __shared__ float csum_lds[2][128];

    const int tid  = threadIdx.x;
    const int wave = tid >> 6;
    const int lane = tid & 63;

    // R1 supertile/XCD swizzle on the full 128x128 block grid; skip lower triangle.
    const int bid    = blockIdx.x;
    const int xcd    = bid & 7;
    const int j      = bid >> 3;
    const int super  = ((j >> 8) << 3) + xcd;                // 0..63
    const int within = j & 255;
    const int brow   = ((super >> 3) << 4) + (within >> 4);  // 0..127
    const int bcol   = ((super & 7) << 4) + (within & 15);   // 0..127
    if (brow > bcol) return;
    const bool isdiag = (brow == bcol);

    const char* gA = (const char*)zq + (size_t)brow * 128 * 256; // fp8 row = 256B
    const char* gB = (const char*)zq + (size_t)bcol * 128 * 256;

    const int quad = lane >> 4;
    const int l15  = lane & 15;
    const int wr   = wave >> 1, wc = wave & 1;

    f32x4 zero = {0.f, 0.f, 0.f, 0.f};
    f32x4 acc[4][4];
#pragma unroll
    for (int a = 0; a < 4; ++a)
#pragma unroll
        for (int b = 0; b < 4; ++b) acc[a][b] = zero;

    const int strow = lane >> 3;  // row within 8-row chunk
    const int sslot = lane & 7;   // swizzled granule slot this lane fills

#pragma unroll
    for (int ko = 0; ko < 2; ++ko) {      // K = 2 x 128
        // stage A and B 128x128 fp8 slices (16KB each); 4+4 1KB wave-loads per wave
#pragma unroll
        for (int s4 = 0; s4 < 4; ++s4) {
            int t   = (wave << 2) + s4;        // chunk 0..15 (8 rows each)
            int row = (t << 3) + strow;        // 0..127
            int g   = sslot ^ (row & 7);       // global granule to fetch
            size_t goff = (size_t)row * 256 + ko * 128 + g * 16;
            __builtin_amdgcn_global_load_lds(
                (const __attribute__((address_space(1))) unsigned int*)(gA + goff),
                (__attribute__((address_space(3))) unsigned int*)(lds + t * 1024),
                16, 0, 0);
            __builtin_amdgcn_global_load_lds(
                (const __attribute__((address_space(1))) unsigned int*)(gB + goff),
                (__attribute__((address_space(3))) unsigned int*)(lds + 16384 + t * 1024),
                16, 0, 0);
        }
        __syncthreads();

        i32x8 af[4], bfr[4];
#pragma unroll
        for (int t = 0; t < 4; ++t) {
            const int arow = (wr << 6) + (t << 4) + l15;     // LDS-local A row
            const int abase = arow << 7;                     // *128
            const int s0 = ((quad << 1) ^ (arow & 7)) << 4;
            const int s1 = (((quad << 1) | 1) ^ (arow & 7)) << 4;
            i32x4 lo = *(const i32x4*)(lds + abase + s0);
            i32x4 hi = *(const i32x4*)(lds + abase + s1);
            i32x8 f;
            f[0] = lo[0]; f[1] = lo[1]; f[2] = lo[2]; f[3] = lo[3];
            f[4] = hi[0]; f[5] = hi[1]; f[6] = hi[2]; f[7] = hi[3];
            af[t] = f;

            const int brw   = (wc << 6) + (t << 4) + l15;    // LDS-local B row
            const int bbase = 16384 + (brw << 7);
            const int t0 = ((quad << 1) ^ (brw & 7)) << 4;
            const int t1 = (((quad << 1) | 1) ^ (brw & 7)) << 4;
            i32x4 blo = *(const i32x4*)(lds + bbase + t0);
            i32x4 bhi = *(const i32x4*)(lds + bbase + t1);
            i32x8 g2;
            g2[0] = blo[0]; g2[1] = blo[1]; g2[2] = blo[2]; g2[3] = blo[3];
            g2[4] = bhi[0]; g2[5] = bhi[1]; g2[6] = bhi[2]; g2[7] = bhi[3];
            bfr[t] = g2;
        }
#pragma unroll
        for (int rt = 0; rt < 4; ++rt)
#pragma unroll
            for (int ct = 0; ct < 4; ++ct)
                acc[rt][ct] = __builtin_amdgcn_mfma_scale_f32_16x16x128_f8f6f4(
                    af[rt], bfr[ct], acc[rt][ct],
                    0, 0,          // cbsz=fp8(e4m3), blgp=fp8(e4m3)
                    0, 127,        // A scale: opsel 0, e8m0 127 = 1.0
                    0, 127);       // B scale: opsel 0, e8m0 127 = 1.0
        __syncthreads();
    }

    // epilogue: e = exp(2*dot) = exp2(acc * 2/ln2); mask diagonal;
    // row-sums over lane&15, col-sums over quad. (identical to verified R2)
    const int rb = wr << 6;
    const int cb = wc << 6;
    float cs[4] = {0.f, 0.f, 0.f, 0.f};
#pragma unroll
    for (int rt = 0; rt < 4; ++rt) {
        float rs[4] = {0.f, 0.f, 0.f, 0.f};
        const int rtile = rb + (rt << 4);
#pragma unroll
        for (int ct = 0; ct < 4; ++ct) {
            const int ctile = cb + (ct << 4);
            const bool tdiag = isdiag && (rtile == ctile);
#pragma unroll
            for (int r = 0; r < 4; ++r) {
                float e = exp2f(acc[rt][ct][r] * TWO_OVER_LN2);
                if (tdiag && ((quad << 2) + r) == l15) e = 0.f; // self-sim
                rs[r] += e;
                cs[ct] += e;
            }
        }
#pragma unroll
        for (int m = 1; m <= 8; m <<= 1)
#pragma unroll
            for (int r = 0; r < 4; ++r) rs[r] += __shfl_xor(rs[r], m, 64);
        if (l15 == 0) {
            int lrow = rb + (rt << 4) + (quad << 2);
#pragma unroll
            for (int r = 0; r < 4; ++r) rsum_lds[wc][lrow + r] = rs[r];
        }
    }
#pragma unroll
    for (int m = 16; m <= 32; m <<= 1)
#pragma unroll
        for (int ct = 0; ct < 4; ++ct) cs[ct] += __shfl_xor(cs[ct], m, 64);
    if (quad == 0) {
#pragma unroll
        for (int ct = 0; ct < 4; ++ct) csum_lds[wr][cb + (ct << 4) + l15] = cs[ct];
    }
    __syncthreads();
    if (tid < 128) {
        float rv = rsum_lds[0][tid] + rsum_lds[1][tid];
        part[(size_t)bcol * NTOT + brow * 128 + tid] = rv;
        if (!isdiag) {
            float cv = csum_lds[0][tid] + csum_lds[1][tid];
            part[(size_t)brow * NTOT + bcol * 128 + tid] = cv;
        }
    }
}

// ---------------- kernel 3: reduce partials per row, take log ----------------
__global__ __launch_bounds__(256) void rowlog(const float* __restrict__ part,
                                              float* __restrict__ logpart) {
    const int row = blockIdx.x * 256 + threadIdx.x;
    float s = 0.f;
    for (int c = 0; c < 128; ++c) s += part[(size_t)c * NTOT + row];
    float lg = logf(s + 1e-12f);
#pragma unroll
    for (int m = 32; m >= 1; m >>= 1) lg += __shfl_xor(lg, m, 64);
    __shared__ float red[4];
    const int wave = threadIdx.x >> 6, lane = threadIdx.x & 63;
    if (lane == 0) red[wave] = lg;
    __syncthreads();
    if (threadIdx.x == 0) logpart[blockIdx.x] = red[0] + red[1] + red[2] + red[3];
}

// ---------------- kernel 4: finalize ----------------
__global__ __launch_bounds__(256) void finalk(const float* __restrict__ pospart,
                                              const float* __restrict__ logpart,
                                              float* __restrict__ out) {
    const int t = threadIdx.x;
    float sp = 0.f, sl = 0.f;
    for (int k = t; k < 4096; k += 256) sp += pospart[k];
    if (t < 64) sl = logpart[t];
#pragma unroll
    for (int m = 32; m >= 1; m >>= 1) { sp += __shfl_xor(sp, m, 64); sl += __shfl_xor(sl, m, 64); }
    __shared__ float rp[4], rl[4];
    const int wave = t >> 6, lane = t & 63;
    if (lane == 0) { rp[wave] = sp; rl[wave] = sl; }
    __syncthreads();
    if (t == 0) {
        float P = rp[0] + rp[1] + rp[2] + rp[3];
        float L = rl[0] + rl[1] + rl[2] + rl[3];
        out[0] = (L - P) / 16384.0f;
    }
}

extern "C" void kernel_launch(void* const* d_in, const int* in_sizes, int n_in,
                              void* d_out, int out_size, void* d_ws, size_t ws_size,
                              hipStream_t stream) {
    const float* z1 = (const float*)d_in[0];
    const float* z2 = (const float*)d_in[1];
    const float* z3 = (const float*)d_in[2];
    const float* z4 = (const float*)d_in[3];
    float* out = (float*)d_out;

    char* ws = (char*)d_ws;
    unsigned int* zq = (unsigned int*)ws;                        // 4 MB (fp8)
    float* part    = (float*)(ws + (size_t)(4u << 20));          // 8 MB
    float* pospart = (float*)(ws + (size_t)(12u << 20));         // 16 KB
    float* logpart = (float*)(ws + (size_t)(12u << 20) + 16384); // 256 B

    norm4k<<<1024, 256, 0, stream>>>(z1, z2, z3, z4, zq, pospart);
    tilek<<<16384, 256, 0, stream>>>((const unsigned char*)zq, part);
    rowlog<<<64, 256, 0, stream>>>(part, logpart);
    finalk<<<1, 256, 0, stream>>>(pospart, logpart, out);
}